// Round 6
// baseline (468.913 us; speedup 1.0000x reference)
//
#include <hip/hip_runtime.h>

#define GLOBAL_AS __attribute__((address_space(1)))
#define LDS_AS    __attribute__((address_space(3)))

typedef __bf16 bf16x8 __attribute__((ext_vector_type(8)));
typedef float  f32x4  __attribute__((ext_vector_type(4)));

// Problem dims (fixed by the reference)
constexpr int SRC_STRIDE = 8192 * 80;         // floats per batch row: 655360
constexpr int TOUT       = 2728;              // output time steps
constexpr long OUT_ELEMS = (long)TOUT * 16 * 1024;  // 44695552
constexpr int SRC_ELEMS  = 32 * SRC_STRIDE;   // 20971520
constexpr int W_ELEMS    = 1024 * 640;        // 655360
constexpr int MBLK       = 682;               // ceil(87296/128)

__device__ __forceinline__ unsigned short f2bf(float f) {
    union { float f; unsigned u; } a; a.f = f;
    unsigned r = a.u + 0x7FFF + ((a.u >> 16) & 1);   // round-to-nearest-even
    return (unsigned short)(r >> 16);
}

// fp32 -> bf16 conversion, 4 elements/thread
__global__ void cvt_kernel(const float* __restrict__ in, unsigned short* __restrict__ out, int n4) {
    int i = blockIdx.x * blockDim.x + threadIdx.x;
    if (i >= n4) return;
    float4 v = ((const float4*)in)[i];
    ushort4 o;
    o.x = f2bf(v.x); o.y = f2bf(v.y); o.z = f2bf(v.z); o.w = f2bf(v.w);
    ((ushort4*)out)[i] = o;
}

// out_lengths = src_lengths // 3 - 2, written as fp32 after the main output
__global__ void lengths_kernel(const int* __restrict__ len, float* __restrict__ out) {
    int i = threadIdx.x;
    if (i < 32) out[OUT_ELEMS + i] = (float)(len[i] / 3 - 2);
}

// Fused GEMM (M=87296, N=1024, K=640) + bias + GLU epilogue.
// Structure = the verified 126.9us baseline (128x128 tile, 4 waves 2Mx2N,
// BK=64, two __syncthreads per K-step, compiler-scheduled inner loop), with
// ONE change: B (the 1.3 MB weight matrix, fully L2-resident) is no longer
// staged through LDS. B-fragments are loaded per-(kb,ks) directly from
// global memory into registers -- same values the old LDS path delivered
// (n*640 + kb*64 + ks*32 + (lane>>4)*8), no swizzle needed. This HALVES the
// LDS traffic (the measured bottleneck: 5.28 GB -> 2.64 GB; R0 ran at 60%
// of the 69 TB/s LDS ceiling), halves the DMA the barrier drain waits on,
// and shrinks LDS to 16 KB so 4 blocks/CU can co-reside (launch_bounds 4).
// A[m][k] = srcb[(m%32)*655360 + (m/32)*240 + k]  (bf16, contiguous rows)
// B[n][k] = wb[n*640 + k]                          (bf16, N x K row-major)
// out[(t*16+b)*1024+n] = y[t*32+b][n] * sigmoid(y[t*32+b+16][n])
__global__ __launch_bounds__(256, 4)
void glu_gemm(const __bf16* __restrict__ A,
              const __bf16* __restrict__ Wb,
              const float* __restrict__ bias,
              float* __restrict__ out) {
    __shared__ __bf16 lA[128 * 64];   // 16 KB, rows of 64 bf16, chunk-swizzled

    const int tid  = threadIdx.x;
    const int lane = tid & 63;
    const int w    = tid >> 6;        // wave 0..3
    const int wm   = w & 1;           // wave M position (2x2 wave grid)
    const int wn   = w >> 1;

    // XCD-aware swizzle: all 8 bn-siblings (which share one A-tile) get the
    // same bid%8 -> same XCD L2, consecutively numbered (temporal locality).
    const int bid = blockIdx.x;
    const int bn  = (bid >> 3) & 7;
    const int bm  = (bid >> 6) * 8 + (bid & 7);
    if (bm >= MBLK) return;           // tail of last partial group (48 idle blocks)

    // ---- A staging address setup (global_load_lds: uniform LDS base + lane*16B) ----
    // issue j covers rows w*32 + j*8 .. +7; lane -> row (lane>>3), physical chunk (lane&7)
    // swizzle: physical chunk p holds logical chunk c = p ^ (row&7)
    const int c8 = (((lane & 7) ^ (lane >> 3)) * 8);   // logical chunk start (elements)
    int aoff_g[4];
#pragma unroll
    for (int j = 0; j < 4; ++j) {
        int r = w * 32 + j * 8 + (lane >> 3);
        int m = bm * 128 + r;
        int t = m >> 5, b = m & 31;
        aoff_g[j] = b * SRC_STRIDE + t * 240 + c8;
    }

    // ---- A fragment read offsets (verified) ----
    const int q    = lane >> 4;                        // k-chunk 0..3
    const int poff = ((q ^ (lane & 7)) * 8);           // ks=0 physical chunk * 8 elems
    int aoff_l[4];
#pragma unroll
    for (int i = 0; i < 4; ++i)
        aoff_l[i] = (wm * 64 + i * 16 + (lane & 15)) * 64;

    // ---- B fragment global base: col = lane&15, k-chunk = q ----
    const __bf16* bgp = Wb + ((bn * 128 + wn * 64 + (lane & 15)) * 640 + q * 8);

    f32x4 acc[4][4] = {};

    for (int kb = 0; kb < 10; ++kb) {
        const int k0 = kb * 64;
#pragma unroll
        for (int j = 0; j < 4; ++j)
            __builtin_amdgcn_global_load_lds(
                (const GLOBAL_AS void*)(A + (aoff_g[j] + k0)),
                (LDS_AS void*)(lA + (w * 32 + j * 8) * 64), 16, 0, 0);
        __syncthreads();
#pragma unroll
        for (int ks = 0; ks < 2; ++ks) {
            const int po = poff ^ (ks << 5);           // (p0 ^ 4)*8 == p0*8 ^ 32
            bf16x8 af[4], bq[4];
#pragma unroll
            for (int i = 0; i < 4; ++i)
                af[i] = *(const bf16x8*)(lA + aoff_l[i] + po);
#pragma unroll
            for (int i = 0; i < 4; ++i)
                bq[i] = *(const bf16x8*)(bgp + i * (16 * 640) + k0 + ks * 32);
#pragma unroll
            for (int mt = 0; mt < 4; ++mt)
#pragma unroll
                for (int nt = 0; nt < 4; ++nt)
                    acc[mt][nt] = __builtin_amdgcn_mfma_f32_16x16x32_bf16(
                        af[mt], bq[nt], acc[mt][nt], 0, 0, 0);
        }
        __syncthreads();
    }

    // ---- epilogue: bias + GLU (value row m pairs with gate row m+16; same lane/reg) ----
    const int col = lane & 15;
    float bv[4];
#pragma unroll
    for (int nt = 0; nt < 4; ++nt)
        bv[nt] = bias[bn * 128 + wn * 64 + nt * 16 + col];

    const int t_base = bm * 4 + wm * 2;
#pragma unroll
    for (int pr = 0; pr < 2; ++pr) {                   // two t-groups per wave tile
        const int t = t_base + pr;
#pragma unroll
        for (int nt = 0; nt < 4; ++nt) {
            const int n = bn * 128 + wn * 64 + nt * 16 + col;
#pragma unroll
            for (int r2 = 0; r2 < 4; ++r2) {
                const int brow = q * 4 + r2;           // b in 0..15 (value rows)
                float v = acc[pr * 2 + 0][nt][r2] + bv[nt];
                float g = acc[pr * 2 + 1][nt][r2] + bv[nt];
                float s = 1.0f / (1.0f + __expf(-g));
                out[((long)(t * 16 + brow)) * 1024 + n] = v * s;
            }
        }
    }
}

extern "C" void kernel_launch(void* const* d_in, const int* in_sizes, int n_in,
                              void* d_out, int out_size, void* d_ws, size_t ws_size,
                              hipStream_t stream) {
    const float* src  = (const float*)d_in[0];
    const int*   lens = (const int*)d_in[1];
    const float* Wf   = (const float*)d_in[2];
    const float* bias = (const float*)d_in[3];
    float* out = (float*)d_out;

    unsigned short* srcb = (unsigned short*)d_ws;          // 20971520 bf16 = 41.9 MB
    unsigned short* wb   = srcb + SRC_ELEMS;               // 655360 bf16 = 1.3 MB

    // bf16 pre-pass (src + W)
    cvt_kernel<<<SRC_ELEMS / 4 / 256, 256, 0, stream>>>(src, srcb, SRC_ELEMS / 4);
    cvt_kernel<<<W_ELEMS / 4 / 256, 256, 0, stream>>>(Wf, wb, W_ELEMS / 4);

    // out_lengths
    lengths_kernel<<<1, 64, 0, stream>>>(lens, out);

    // fused GEMM + GLU: 86 groups x (8 bn x 8 bm_local) = 5504 blocks (48 idle tail)
    glu_gemm<<<86 * 64, 256, 0, stream>>>((const __bf16*)srcb, (const __bf16*)wb, bias, out);
}

// Round 7
// 468.023 us; speedup vs baseline: 1.0019x; 1.0019x over previous
//
#include <hip/hip_runtime.h>

#define GLOBAL_AS __attribute__((address_space(1)))
#define LDS_AS    __attribute__((address_space(3)))

typedef __bf16 bf16x8 __attribute__((ext_vector_type(8)));
typedef float  f32x4  __attribute__((ext_vector_type(4)));

// Problem dims (fixed by the reference)
constexpr int SRC_STRIDE = 8192 * 80;         // floats per batch row: 655360
constexpr int TOUT       = 2728;              // output time steps
constexpr long OUT_ELEMS = (long)TOUT * 16 * 1024;  // 44695552
constexpr int SRC_ELEMS  = 32 * SRC_STRIDE;   // 20971520
constexpr int W_ELEMS    = 1024 * 640;        // 655360
constexpr int MBLK       = 682;               // ceil(87296/128)
constexpr int NB_SRC     = SRC_ELEMS / 4 / 256;   // 20480 cvt blocks for src
constexpr int NB_W       = W_ELEMS / 4 / 256;     // 640 cvt blocks for W

__device__ __forceinline__ unsigned short f2bf(float f) {
    union { float f; unsigned u; } a; a.f = f;
    unsigned r = a.u + 0x7FFF + ((a.u >> 16) & 1);   // round-to-nearest-even
    return (unsigned short)(r >> 16);
}

// Fused pre-pass: src->bf16, W->bf16, out_lengths. One launch instead of three.
// Block ranges: [0, NB_SRC) src cvt; [NB_SRC, NB_SRC+NB_W) W cvt; last block lengths.
__global__ void prep_kernel(const float* __restrict__ src, const float* __restrict__ Wf,
                            const int* __restrict__ len,
                            unsigned short* __restrict__ srcb, unsigned short* __restrict__ wb,
                            float* __restrict__ out) {
    const int b = blockIdx.x;
    if (b < NB_SRC) {
        int i = b * blockDim.x + threadIdx.x;
        float4 v = ((const float4*)src)[i];
        ushort4 o;
        o.x = f2bf(v.x); o.y = f2bf(v.y); o.z = f2bf(v.z); o.w = f2bf(v.w);
        ((ushort4*)srcb)[i] = o;
    } else if (b < NB_SRC + NB_W) {
        int i = (b - NB_SRC) * blockDim.x + threadIdx.x;
        float4 v = ((const float4*)Wf)[i];
        ushort4 o;
        o.x = f2bf(v.x); o.y = f2bf(v.y); o.z = f2bf(v.z); o.w = f2bf(v.w);
        ((ushort4*)wb)[i] = o;
    } else {
        int i = threadIdx.x;
        if (i < 32) out[OUT_ELEMS + i] = (float)(len[i] / 3 - 2);
    }
}

// one K-step: stage A(kb_) into LDS, prefetch B(kb_+1) into BQN regs, sync,
// MFMA with BQC (loaded last iteration), sync. Skeleton == verified R0 loop.
#define KB_BODY(kb_, BQC, BQN) do {                                              \
    const int k0 = (kb_) * 64;                                                   \
    _Pragma("unroll")                                                            \
    for (int j = 0; j < 4; ++j)                                                  \
        __builtin_amdgcn_global_load_lds(                                        \
            (const GLOBAL_AS void*)(A + (aoff_g[j] + k0)),                       \
            (LDS_AS void*)(lA + (w * 32 + j * 8) * 64), 16, 0, 0);               \
    if ((kb_) < 9) {                                                             \
        _Pragma("unroll")                                                        \
        for (int i = 0; i < 8; ++i)                                              \
            BQN[i] = *(const bf16x8*)(bgp + (i & 3) * (16 * 640)                 \
                                          + (k0 + 64) + (i >> 2) * 32);          \
    }                                                                            \
    __syncthreads();                                                             \
    _Pragma("unroll")                                                            \
    for (int ks = 0; ks < 2; ++ks) {                                             \
        const int po = poff ^ (ks << 5);                                         \
        bf16x8 af[4];                                                            \
        _Pragma("unroll")                                                        \
        for (int i = 0; i < 4; ++i)                                              \
            af[i] = *(const bf16x8*)(lA + aoff_l[i] + po);                       \
        _Pragma("unroll")                                                        \
        for (int mt = 0; mt < 4; ++mt)                                           \
            _Pragma("unroll")                                                    \
            for (int nt = 0; nt < 4; ++nt)                                       \
                acc[mt][nt] = __builtin_amdgcn_mfma_f32_16x16x32_bf16(           \
                    af[mt], BQC[ks * 4 + nt], acc[mt][nt], 0, 0, 0);             \
    }                                                                            \
    __syncthreads();                                                             \
} while (0)

// Fused GEMM (M=87296, N=1024, K=640) + bias + GLU epilogue.
// Structure = the verified 126.9us baseline (128x128 tile, 4 waves 2Mx2N,
// BK=64, two __syncthreads per K-step, compiler-scheduled inner loop), with
// ONE structural change: B (1.3 MB, L2-resident) skips LDS and is loaded
// into REGISTERS one full K-step ahead (double-buffered bqA/bqB). The loads
// issue before __syncthreads, whose vmcnt(0) drain already waits for the
// A-DMA HBM round trip -- B's L2 latency hides under that existing wait
// (this is what R6 lacked: it loaded B right before use, exposing the
// latency serially -> 267us). LDS traffic halves (the measured bottleneck:
// ds_read ~13.6 MB/CU at ~85 B/cy ~ the R0 critical path); LDS = 16 KB.
// A[m][k] = srcb[(m%32)*655360 + (m/32)*240 + k]  (bf16, contiguous rows)
// B[n][k] = wb[n*640 + k]                          (bf16, N x K row-major)
// out[(t*16+b)*1024+n] = y[t*32+b][n] * sigmoid(y[t*32+b+16][n])
__global__ __launch_bounds__(256, 3)
void glu_gemm(const __bf16* __restrict__ A,
              const __bf16* __restrict__ Wb,
              const float* __restrict__ bias,
              float* __restrict__ out) {
    __shared__ __bf16 lA[128 * 64];   // 16 KB, rows of 64 bf16, chunk-swizzled

    const int tid  = threadIdx.x;
    const int lane = tid & 63;
    const int w    = tid >> 6;        // wave 0..3
    const int wm   = w & 1;           // wave M position (2x2 wave grid)
    const int wn   = w >> 1;

    // XCD-aware swizzle: all 8 bn-siblings (which share one A-tile) get the
    // same bid%8 -> same XCD L2, consecutively numbered (temporal locality).
    const int bid = blockIdx.x;
    const int bn  = (bid >> 3) & 7;
    const int bm  = (bid >> 6) * 8 + (bid & 7);
    if (bm >= MBLK) return;           // tail of last partial group (48 idle blocks)

    // ---- A staging address setup (global_load_lds: uniform LDS base + lane*16B) ----
    // issue j covers rows w*32 + j*8 .. +7; lane -> row (lane>>3), physical chunk (lane&7)
    // swizzle: physical chunk p holds logical chunk c = p ^ (row&7)
    const int c8 = (((lane & 7) ^ (lane >> 3)) * 8);   // logical chunk start (elements)
    int aoff_g[4];
#pragma unroll
    for (int j = 0; j < 4; ++j) {
        int r = w * 32 + j * 8 + (lane >> 3);
        int m = bm * 128 + r;
        int t = m >> 5, b = m & 31;
        aoff_g[j] = b * SRC_STRIDE + t * 240 + c8;
    }

    // ---- A fragment read offsets (verified) ----
    const int q    = lane >> 4;                        // k-chunk 0..3
    const int poff = ((q ^ (lane & 7)) * 8);           // ks=0 physical chunk * 8 elems
    int aoff_l[4];
#pragma unroll
    for (int i = 0; i < 4; ++i)
        aoff_l[i] = (wm * 64 + i * 16 + (lane & 15)) * 64;

    // ---- B fragment global base (verified in R6): col = lane&15, k-chunk = q ----
    const __bf16* bgp = Wb + ((bn * 128 + wn * 64 + (lane & 15)) * 640 + q * 8);

    f32x4 acc[4][4] = {};
    bf16x8 bqA[8], bqB[8];

    // prologue: load B frags for kb=0 into set A
#pragma unroll
    for (int i = 0; i < 8; ++i)
        bqA[i] = *(const bf16x8*)(bgp + (i & 3) * (16 * 640) + (i >> 2) * 32);

#pragma unroll 1
    for (int kbb = 0; kbb < 5; ++kbb) {
        KB_BODY(2 * kbb,     bqA, bqB);
        KB_BODY(2 * kbb + 1, bqB, bqA);
    }

    // ---- epilogue: bias + GLU (value row m pairs with gate row m+16; same lane/reg) ----
    const int col = lane & 15;
    float bv[4];
#pragma unroll
    for (int nt = 0; nt < 4; ++nt)
        bv[nt] = bias[bn * 128 + wn * 64 + nt * 16 + col];

    const int t_base = bm * 4 + wm * 2;
#pragma unroll
    for (int pr = 0; pr < 2; ++pr) {                   // two t-groups per wave tile
        const int t = t_base + pr;
#pragma unroll
        for (int nt = 0; nt < 4; ++nt) {
            const int n = bn * 128 + wn * 64 + nt * 16 + col;
#pragma unroll
            for (int r2 = 0; r2 < 4; ++r2) {
                const int brow = q * 4 + r2;           // b in 0..15 (value rows)
                float v = acc[pr * 2 + 0][nt][r2] + bv[nt];
                float g = acc[pr * 2 + 1][nt][r2] + bv[nt];
                float s = 1.0f / (1.0f + __expf(-g));
                out[((long)(t * 16 + brow)) * 1024 + n] = v * s;
            }
        }
    }
}

extern "C" void kernel_launch(void* const* d_in, const int* in_sizes, int n_in,
                              void* d_out, int out_size, void* d_ws, size_t ws_size,
                              hipStream_t stream) {
    const float* src  = (const float*)d_in[0];
    const int*   lens = (const int*)d_in[1];
    const float* Wf   = (const float*)d_in[2];
    const float* bias = (const float*)d_in[3];
    float* out = (float*)d_out;

    unsigned short* srcb = (unsigned short*)d_ws;          // 20971520 bf16 = 41.9 MB
    unsigned short* wb   = srcb + SRC_ELEMS;               // 655360 bf16 = 1.3 MB

    // fused pre-pass: src cvt + W cvt + out_lengths in ONE launch
    prep_kernel<<<NB_SRC + NB_W + 1, 256, 0, stream>>>(src, Wf, lens, srcb, wb, out);

    // fused GEMM + GLU: 86 groups x (8 bn x 8 bm_local) = 5504 blocks (48 idle tail)
    glu_gemm<<<86 * 64, 256, 0, stream>>>((const __bf16*)srcb, (const __bf16*)wb, bias, out);
}